// Round 8
// baseline (63.126 us; speedup 1.0000x reference)
//
#include <hip/hip_runtime.h>
#include <math.h>

#define NP 4096
#define KNN 6
#define NCHUNK 16
#define CHUNK 256   // NP / NCHUNK

typedef unsigned int u32;
typedef unsigned long long u64;

__device__ inline double wave_reduce(double v) {
#pragma unroll
  for (int o = 32; o > 0; o >>= 1) v += __shfl_down(v, o);
  return v;
}

__device__ inline float det3f(const float M[3][3]) {
  return M[0][0]*(M[1][1]*M[2][2]-M[1][2]*M[2][1])
       - M[0][1]*(M[1][0]*M[2][2]-M[1][2]*M[2][0])
       + M[0][2]*(M[1][0]*M[2][1]-M[1][1]*M[2][0]);
}

// Sorted top-6 insert, med3-matchable form: b_i' = min(max(b_{i-1},key), b_i).
// LLVM AMDGPU pattern-matches min(max(a,k),b) -> v_med3_u32 (no inline asm,
// scheduler stays free). All slots read OLD values -> dep depth 2.
#define TOP6_INS(b0,b1,b2,b3,b4,b5,key)                               \
  { u32 n0 = min(b0, key);                                            \
    u32 n1 = min(max(b0, key), b1);                                   \
    u32 n2 = min(max(b1, key), b2);                                   \
    u32 n3 = min(max(b2, key), b3);                                   \
    u32 n4 = min(max(b3, key), b4);                                   \
    u32 n5 = min(max(b4, key), b5);                                   \
    b0 = n0; b1 = n1; b2 = n2; b3 = n3; b4 = n4; b5 = n5; }

// K1: f64 covariance reduce -> f32 Jacobi SVD (thread 0) -> packs BOTH clouds
// as float4 {x,y,z,|p|^2}: cand0 = rigid recon, cand1 = y. Resets ticket.
__global__ __launch_bounds__(256) void k1_kabsch_pack(const float* __restrict__ in,
                                                      const float* __restrict__ sf,
                                                      const float* __restrict__ ycloud,
                                                      float4* __restrict__ cand0,
                                                      float4* __restrict__ cand1,
                                                      u32* __restrict__ counter) {
  const int tid = threadIdx.x;
  const int lane = tid & 63, wv = tid >> 6;
  double acc[15];
#pragma unroll
  for (int q = 0; q < 15; ++q) acc[q] = 0.0;
  for (int i = tid; i < NP; i += 256) {
    double px = in[i], py = in[NP + i], pz = in[2*NP + i];
    double qx = px + (double)sf[i];
    double qy = py + (double)sf[NP + i];
    double qz = pz + (double)sf[2*NP + i];
    acc[0] += px; acc[1] += py; acc[2] += pz;
    acc[3] += qx; acc[4] += qy; acc[5] += qz;
    acc[6] += px*qx; acc[7]  += px*qy; acc[8]  += px*qz;
    acc[9] += py*qx; acc[10] += py*qy; acc[11] += py*qz;
    acc[12]+= pz*qx; acc[13] += pz*qy; acc[14] += pz*qz;
  }
  __shared__ double wred[4][15];
#pragma unroll
  for (int q = 0; q < 15; ++q) {
    double v = wave_reduce(acc[q]);
    if (lane == 0) wred[wv][q] = v;
  }
  __syncthreads();
  __shared__ float Rts[12];
  if (tid == 0) {
    double tot[15];
    for (int q = 0; q < 15; ++q)
      tot[q] = wred[0][q] + wred[1][q] + wred[2][q] + wred[3][q];
    const double invN = 1.0 / (double)NP;
    double cp[3] = { tot[0]*invN, tot[1]*invN, tot[2]*invN };
    double cr[3] = { tot[3]*invN, tot[4]*invN, tot[5]*invN };
    float H[3][3];
    for (int a = 0; a < 3; ++a)
      for (int b = 0; b < 3; ++b)
        H[a][b] = (float)(tot[6 + a*3 + b] - (double)NP * cp[a] * cr[b]);
    float A[3][3];
    for (int a = 0; a < 3; ++a)
      for (int b = 0; b < 3; ++b)
        A[a][b] = H[0][a]*H[0][b] + H[1][a]*H[1][b] + H[2][a]*H[2][b];
    float V[3][3] = {{1,0,0},{0,1,0},{0,0,1}};
    const int PQ[3][2] = {{0,1},{0,2},{1,2}};
    for (int sweep = 0; sweep < 8; ++sweep) {
      for (int r = 0; r < 3; ++r) {
        const int p = PQ[r][0], q = PQ[r][1];
        float apq = A[p][q];
        if (fabsf(apq) > 1e-30f) {
          float theta = (A[q][q] - A[p][p]) / (2.0f * apq);
          float tt = copysignf(1.0f, theta) / (fabsf(theta) + sqrtf(theta*theta + 1.0f));
          float c = 1.0f / sqrtf(tt*tt + 1.0f);
          float s = tt * c;
          for (int k = 0; k < 3; ++k) { float akp=A[k][p], akq=A[k][q]; A[k][p]=c*akp - s*akq; A[k][q]=s*akp + c*akq; }
          for (int k = 0; k < 3; ++k) { float apk=A[p][k], aqk=A[q][k]; A[p][k]=c*apk - s*aqk; A[q][k]=s*apk + c*aqk; }
          for (int k = 0; k < 3; ++k) { float vkp=V[k][p], vkq=V[k][q]; V[k][p]=c*vkp - s*vkq; V[k][q]=s*vkp + c*vkq; }
        }
      }
    }
    int ord[3] = {0,1,2};
    for (int a = 0; a < 2; ++a)
      for (int b = a + 1; b < 3; ++b)
        if (A[ord[b]][ord[b]] > A[ord[a]][ord[a]]) { int t2 = ord[a]; ord[a] = ord[b]; ord[b] = t2; }
    float Vc[3][3], Uc[3][3];
    for (int j = 0; j < 3; ++j) {
      const int e = ord[j];
      float lam = A[e][e] > 0.0f ? A[e][e] : 0.0f;
      float sv = sqrtf(lam);
      float isv = sv > 1e-20f ? 1.0f / sv : 0.0f;
      for (int a = 0; a < 3; ++a) Vc[a][j] = V[a][e];
      for (int a = 0; a < 3; ++a)
        Uc[a][j] = (H[a][0]*Vc[0][j] + H[a][1]*Vc[1][j] + H[a][2]*Vc[2][j]) * isv;
    }
    float dd = (det3f(Uc) * det3f(Vc)) >= 0.0f ? 1.0f : -1.0f;
    float R[3][3];
    for (int a = 0; a < 3; ++a)
      for (int b = 0; b < 3; ++b)
        R[a][b] = Vc[a][0]*Uc[b][0] + Vc[a][1]*Uc[b][1] + dd * Vc[a][2]*Uc[b][2];
    for (int a = 0; a < 3; ++a) {
      Rts[a*3+0] = R[a][0]; Rts[a*3+1] = R[a][1]; Rts[a*3+2] = R[a][2];
      Rts[9+a] = (float)(cr[a] - ((double)R[a][0]*cp[0] + (double)R[a][1]*cp[1]
                                  + (double)R[a][2]*cp[2]));
    }
    *counter = 0u;
  }
  __syncthreads();
  const float r0=Rts[0], r1=Rts[1], r2=Rts[2];
  const float r3=Rts[3], r4=Rts[4], r5=Rts[5];
  const float r6=Rts[6], r7=Rts[7], r8=Rts[8];
  const float t0=Rts[9], t1=Rts[10], t2=Rts[11];
  for (int i = tid; i < NP; i += 256) {
    float px = in[i], py = in[NP + i], pz = in[2*NP + i];
    float a = fmaf(r0, px, fmaf(r1, py, fmaf(r2, pz, t0)));
    float b = fmaf(r3, px, fmaf(r4, py, fmaf(r5, pz, t1)));
    float c = fmaf(r6, px, fmaf(r7, py, fmaf(r8, pz, t2)));
    cand0[i] = make_float4(a, b, c, fmaf(a, a, fmaf(b, b, c * c)));
    float yx = ycloud[i], yy = ycloud[NP + i], yz = ycloud[2*NP + i];
    cand1[i] = make_float4(yx, yy, yz, fmaf(yx, yx, fmaf(yy, yy, yz * yz)));
  }
}

// K2: partial top-6, 2 centers per thread. Grid (NCHUNK=16, 8, 2) = 256 blocks.
// Candidates LDS-staged (256 float4 = 4 KB), wave-broadcast ds_read_b128 --
// halved per-center LDS traffic vs 1-center (4 waves/CU x 256 reads).
// d^2 = |c|^2 - 2 c.ct + |ct|^2 clamped at 0; key = bits & ~0xFFF | idx.
__global__ __launch_bounds__(256) void k2_scan(const float4* __restrict__ cand0,
                                               const float4* __restrict__ cand1,
                                               u32* __restrict__ part) {
  __shared__ float4 sc[CHUNK];
  const int tid = threadIdx.x;
  const int chunk = blockIdx.x, cblk = blockIdx.y, cloud = blockIdx.z;
  const int j0 = chunk * CHUNK;
  const float4* __restrict__ cand = cloud ? cand1 : cand0;
  sc[tid] = cand[j0 + tid];
  const int ci0 = cblk * 512 + tid;     // centers ci0 and ci0+256
  const int ci1 = ci0 + 256;
  const float4 ctA = cand0[ci0];
  const float4 ctB = cand0[ci1];
  const float axA = -2.f*ctA.x, ayA = -2.f*ctA.y, azA = -2.f*ctA.z, wA = ctA.w;
  const float axB = -2.f*ctB.x, ayB = -2.f*ctB.y, azB = -2.f*ctB.z, wB = ctB.w;
  __syncthreads();
  u32 a0=~0u,a1=~0u,a2=~0u,a3=~0u,a4=~0u,a5=~0u;
  u32 c0=~0u,c1=~0u,c2=~0u,c3=~0u,c4=~0u,c5=~0u;
#pragma unroll 8
  for (int j = 0; j < CHUNK; ++j) {
    float4 c = sc[j];
    float sA = fmaf(c.x, axA, fmaf(c.y, ayA, fmaf(c.z, azA, c.w))) + wA;
    float sB = fmaf(c.x, axB, fmaf(c.y, ayB, fmaf(c.z, azB, c.w))) + wB;
    sA = fmaxf(sA, 0.f);
    sB = fmaxf(sB, 0.f);
    u32 kA = (__float_as_uint(sA) & 0xFFFFF000u) | (u32)(j0 + j);
    u32 kB = (__float_as_uint(sB) & 0xFFFFF000u) | (u32)(j0 + j);
    TOP6_INS(a0,a1,a2,a3,a4,a5,kA);
    TOP6_INS(c0,c1,c2,c3,c4,c5,kB);
  }
  u32* oA = part + (size_t)(cloud * NCHUNK + chunk) * KNN * NP + ci0;
  oA[0*NP]=a0; oA[1*NP]=a1; oA[2*NP]=a2; oA[3*NP]=a3; oA[4*NP]=a4; oA[5*NP]=a5;
  u32* oB = part + (size_t)(cloud * NCHUNK + chunk) * KNN * NP + ci1;
  oB[0*NP]=c0; oB[1*NP]=c1; oB[2*NP]=c2; oB[3*NP]=c3; oB[4*NP]=c4; oB[5*NP]=c5;
}

// K3: 32 blocks (cloud x center-block) fold 16 chunk-lists, gather neighbor
// coords (float4 loads), publish signed f64 block sums via device atomics;
// the LAST block (ticket) computes the mean and the L1 loss.
__global__ __launch_bounds__(256) void k3_merge_final(const u32* __restrict__ part,
                                                      const float4* __restrict__ cand0,
                                                      const float4* __restrict__ cand1,
                                                      const float* __restrict__ pred,
                                                      double* __restrict__ blockpart,
                                                      u32* __restrict__ counter,
                                                      float* __restrict__ out) {
  const int tid = threadIdx.x;
  const int lane = tid & 63, wv = tid >> 6;
  const int cloud = blockIdx.x >> 4, cblk = blockIdx.x & 15;
  const int ci = cblk * 256 + tid;
  u32 b0=~0u, b1=~0u, b2=~0u, b3=~0u, b4=~0u, b5=~0u;
  for (int c = 0; c < NCHUNK; ++c) {
    const u32* p = part + (size_t)(cloud * NCHUNK + c) * KNN * NP + ci;
#pragma unroll
    for (int e = 0; e < KNN; ++e) {
      u32 key = p[(size_t)e * NP];
      TOP6_INS(b0,b1,b2,b3,b4,b5,key);
    }
  }
  u32 bk[KNN] = { b0, b1, b2, b3, b4, b5 };
  const float4* __restrict__ g = cloud ? cand1 : cand0;
  float s0 = 0.f, s1 = 0.f, s2 = 0.f;
#pragma unroll
  for (int k = 0; k < KNN; ++k) {
    float4 nb = g[bk[k] & 0xFFFu];
    s0 += nb.x; s1 += nb.y; s2 += nb.z;
  }
  const double sgn = cloud ? -1.0 : 1.0;
  double v0 = wave_reduce(sgn * (double)s0);
  double v1 = wave_reduce(sgn * (double)s1);
  double v2 = wave_reduce(sgn * (double)s2);
  __shared__ double wred[4][3];
  __shared__ int lastFlag;
  if (lane == 0) { wred[wv][0] = v0; wred[wv][1] = v1; wred[wv][2] = v2; }
  __syncthreads();
  if (tid == 0) {
    for (int q = 0; q < 3; ++q) {
      double B = wred[0][q] + wred[1][q] + wred[2][q] + wred[3][q];
      atomicExch((u64*)&blockpart[blockIdx.x * 3 + q], (u64)__double_as_longlong(B));
    }
    __threadfence();
    u32 t = atomicAdd(counter, 1u);
    lastFlag = (t == 31u);
  }
  __syncthreads();
  if (!lastFlag) return;

  // ---- finisher: mean laplace diff, then L1 loss ----
  __shared__ double bp[96];
  __threadfence();
  if (tid < 96)
    bp[tid] = __longlong_as_double((long long)atomicAdd((u64*)&blockpart[tid], 0ULL));
  __syncthreads();
  __shared__ float m[3];
  if (tid == 0) {
    double q0 = 0.0, q1 = 0.0, q2 = 0.0;
    for (int b = 0; b < 32; ++b) {
      q0 += bp[b*3 + 0]; q1 += bp[b*3 + 1]; q2 += bp[b*3 + 2];
    }
    const double sc = 0.2 / (double)NP;   // /(k-1), then mean over N
    m[0] = (float)(q0 * sc); m[1] = (float)(q1 * sc); m[2] = (float)(q2 * sc);
  }
  __syncthreads();
  const float m0 = m[0], m1 = m[1], m2 = m[2];
  double s = 0.0;
  for (int i = tid; i < NP; i += 256) {
    float4 rc = cand0[i];
    s += (double)fabsf(rc.x - m0 - pred[i]);
    s += (double)fabsf(rc.y - m1 - pred[NP + i]);
    s += (double)fabsf(rc.z - m2 - pred[2*NP + i]);
  }
  double v = wave_reduce(s);
  __shared__ double fred[4];
  if (lane == 0) fred[wv] = v;
  __syncthreads();
  if (tid == 0)
    out[0] = (float)((fred[0] + fred[1] + fred[2] + fred[3]) / (3.0 * (double)NP));
}

extern "C" void kernel_launch(void* const* d_in, const int* in_sizes, int n_in,
                              void* d_out, int out_size, void* d_ws, size_t ws_size,
                              hipStream_t stream) {
  const float* in   = (const float*)d_in[0];
  const float* sf   = (const float*)d_in[1];
  const float* y1   = (const float*)d_in[2];
  const float* pred = (const float*)d_in[3];

  u32* part = (u32*)d_ws;                                   // 2*16*6*4096 u32 = 3.15 MB
  double* blockpart = (double*)(part + (size_t)2*NCHUNK*KNN*NP);  // 96 doubles
  u32* counter = (u32*)(blockpart + 96);                    // 16 B
  float4* cand0 = (float4*)(counter + 4);                   // NP float4 = 64 KB
  float4* cand1 = cand0 + NP;                               // NP float4 = 64 KB

  k1_kabsch_pack<<<1, 256, 0, stream>>>(in, sf, y1, cand0, cand1, counter);
  k2_scan<<<dim3(NCHUNK, 8, 2), 256, 0, stream>>>(cand0, cand1, part);
  k3_merge_final<<<32, 256, 0, stream>>>(part, cand0, cand1, pred,
                                         blockpart, counter, (float*)d_out);
}

// Round 9
// 55.967 us; speedup vs baseline: 1.1279x; 1.1279x over previous
//
#include <hip/hip_runtime.h>
#include <math.h>

#define NP 4096
#define KNN 6
#define NCHUNK 16
#define CHUNK 256   // NP / NCHUNK

typedef unsigned int u32;
typedef unsigned long long u64;

__device__ inline double wave_reduce(double v) {
#pragma unroll
  for (int o = 32; o > 0; o >>= 1) v += __shfl_down(v, o);
  return v;
}

__device__ inline float det3f(const float M[3][3]) {
  return M[0][0]*(M[1][1]*M[2][2]-M[1][2]*M[2][1])
       - M[0][1]*(M[1][0]*M[2][2]-M[1][2]*M[2][0])
       + M[0][2]*(M[1][0]*M[2][1]-M[1][1]*M[2][0]);
}

// ILP-friendly sorted top-6 insert: b_i' = min(b_i, max(b_{i-1}, key)).
#define TOP6_INSERT_ILP(key)                                          \
  { u32 m0 = max(b0, key), m1 = max(b1, key), m2 = max(b2, key),      \
        m3 = max(b3, key), m4 = max(b4, key);                         \
    b0 = min(b0, key); b1 = min(b1, m0); b2 = min(b2, m1);            \
    b3 = min(b3, m2); b4 = min(b4, m3); b5 = min(b5, m4); }

// K1: f64 covariance reduce -> f32 Jacobi SVD (thread 0) -> writes R(9)+t(3)
// floats to ws and resets the finisher ticket counter.
__global__ __launch_bounds__(256) void k1_kabsch(const float* __restrict__ in,
                                                 const float* __restrict__ sf,
                                                 float* __restrict__ Rt,
                                                 u32* __restrict__ counter) {
  const int tid = threadIdx.x;
  const int lane = tid & 63, wv = tid >> 6;
  double acc[15];
#pragma unroll
  for (int q = 0; q < 15; ++q) acc[q] = 0.0;
  for (int i = tid; i < NP; i += 256) {
    double px = in[i], py = in[NP + i], pz = in[2*NP + i];
    double qx = px + (double)sf[i];
    double qy = py + (double)sf[NP + i];
    double qz = pz + (double)sf[2*NP + i];
    acc[0] += px; acc[1] += py; acc[2] += pz;
    acc[3] += qx; acc[4] += qy; acc[5] += qz;
    acc[6] += px*qx; acc[7]  += px*qy; acc[8]  += px*qz;
    acc[9] += py*qx; acc[10] += py*qy; acc[11] += py*qz;
    acc[12]+= pz*qx; acc[13] += pz*qy; acc[14] += pz*qz;
  }
  __shared__ double wred[4][15];
#pragma unroll
  for (int q = 0; q < 15; ++q) {
    double v = wave_reduce(acc[q]);
    if (lane == 0) wred[wv][q] = v;
  }
  __syncthreads();
  if (tid == 0) {
    double tot[15];
    for (int q = 0; q < 15; ++q)
      tot[q] = wred[0][q] + wred[1][q] + wred[2][q] + wred[3][q];
    const double invN = 1.0 / (double)NP;
    double cp[3] = { tot[0]*invN, tot[1]*invN, tot[2]*invN };
    double cr[3] = { tot[3]*invN, tot[4]*invN, tot[5]*invN };
    float H[3][3];
    for (int a = 0; a < 3; ++a)
      for (int b = 0; b < 3; ++b)
        H[a][b] = (float)(tot[6 + a*3 + b] - (double)NP * cp[a] * cr[b]);
    // A = H^T H, f32 Jacobi eigendecomposition -> V
    float A[3][3];
    for (int a = 0; a < 3; ++a)
      for (int b = 0; b < 3; ++b)
        A[a][b] = H[0][a]*H[0][b] + H[1][a]*H[1][b] + H[2][a]*H[2][b];
    float V[3][3] = {{1,0,0},{0,1,0},{0,0,1}};
    const int PQ[3][2] = {{0,1},{0,2},{1,2}};
    for (int sweep = 0; sweep < 8; ++sweep) {
      for (int r = 0; r < 3; ++r) {
        const int p = PQ[r][0], q = PQ[r][1];
        float apq = A[p][q];
        if (fabsf(apq) > 1e-30f) {
          float theta = (A[q][q] - A[p][p]) / (2.0f * apq);
          float tt = copysignf(1.0f, theta) / (fabsf(theta) + sqrtf(theta*theta + 1.0f));
          float c = 1.0f / sqrtf(tt*tt + 1.0f);
          float s = tt * c;
          for (int k = 0; k < 3; ++k) { float akp=A[k][p], akq=A[k][q]; A[k][p]=c*akp - s*akq; A[k][q]=s*akp + c*akq; }
          for (int k = 0; k < 3; ++k) { float apk=A[p][k], aqk=A[q][k]; A[p][k]=c*apk - s*aqk; A[q][k]=s*apk + c*aqk; }
          for (int k = 0; k < 3; ++k) { float vkp=V[k][p], vkq=V[k][q]; V[k][p]=c*vkp - s*vkq; V[k][q]=s*vkp + c*vkq; }
        }
      }
    }
    int ord[3] = {0,1,2};
    for (int a = 0; a < 2; ++a)
      for (int b = a + 1; b < 3; ++b)
        if (A[ord[b]][ord[b]] > A[ord[a]][ord[a]]) { int t2 = ord[a]; ord[a] = ord[b]; ord[b] = t2; }
    float Vc[3][3], Uc[3][3];
    for (int j = 0; j < 3; ++j) {
      const int e = ord[j];
      float lam = A[e][e] > 0.0f ? A[e][e] : 0.0f;
      float sv = sqrtf(lam);
      float isv = sv > 1e-20f ? 1.0f / sv : 0.0f;
      for (int a = 0; a < 3; ++a) Vc[a][j] = V[a][e];
      for (int a = 0; a < 3; ++a)
        Uc[a][j] = (H[a][0]*Vc[0][j] + H[a][1]*Vc[1][j] + H[a][2]*Vc[2][j]) * isv;
    }
    float dd = (det3f(Uc) * det3f(Vc)) >= 0.0f ? 1.0f : -1.0f;
    float R[3][3];
    for (int a = 0; a < 3; ++a)
      for (int b = 0; b < 3; ++b)
        R[a][b] = Vc[a][0]*Uc[b][0] + Vc[a][1]*Uc[b][1] + dd * Vc[a][2]*Uc[b][2];
    for (int a = 0; a < 3; ++a) {
      Rt[a*3+0] = R[a][0]; Rt[a*3+1] = R[a][1]; Rt[a*3+2] = R[a][2];
      Rt[9+a] = (float)(cr[a] - ((double)R[a][0]*cp[0] + (double)R[a][1]*cp[1]
                                 + (double)R[a][2]*cp[2]));
    }
    *counter = 0u;
  }
}

// K2: partial top-6 per (cloud, ref-chunk, center-block). Grid (16,16,2).
// Recon is computed in-kernel from R,t (no global round-trip); 16 designated
// blocks (cloud 0, chunk==cblk) materialize rx/ry/rz for the later gathers.
// Key = monotone-u32(|c|^2 - 2 c.x) truncated, low 12 bits = candidate index.
__global__ __launch_bounds__(256) void k2_scan(const float* __restrict__ in,
                                               const float* __restrict__ ycloud,
                                               const float* __restrict__ Rt,
                                               u32* __restrict__ part,
                                               float* __restrict__ rx,
                                               float* __restrict__ ry,
                                               float* __restrict__ rz) {
  __shared__ float4 sc[CHUNK];
  __shared__ float Rts[12];
  const int tid = threadIdx.x;
  const int chunk = blockIdx.x, cblk = blockIdx.y, cloud = blockIdx.z;
  if (tid < 12) Rts[tid] = Rt[tid];
  __syncthreads();
  const float r0=Rts[0], r1=Rts[1], r2=Rts[2];
  const float r3=Rts[3], r4=Rts[4], r5=Rts[5];
  const float r6=Rts[6], r7=Rts[7], r8=Rts[8];
  const float t0=Rts[9], t1=Rts[10], t2=Rts[11];
  const int j0 = chunk * CHUNK;
  {
    const int jj = j0 + tid;
    float a, b, c;
    if (cloud == 0) {
      float px = in[jj], py = in[NP + jj], pz = in[2*NP + jj];
      a = fmaf(r0, px, fmaf(r1, py, fmaf(r2, pz, t0)));
      b = fmaf(r3, px, fmaf(r4, py, fmaf(r5, pz, t1)));
      c = fmaf(r6, px, fmaf(r7, py, fmaf(r8, pz, t2)));
      if (chunk == cblk) { rx[jj] = a; ry[jj] = b; rz[jj] = c; }
    } else {
      a = ycloud[jj]; b = ycloud[NP + jj]; c = ycloud[2*NP + jj];
    }
    sc[tid] = make_float4(a, b, c, fmaf(a, a, fmaf(b, b, c * c)));
  }
  // center = rigid recon of ci (recomputed, not loaded)
  const int ci = cblk * CHUNK + tid;
  float cx, cy, cz;
  {
    float px = in[ci], py = in[NP + ci], pz = in[2*NP + ci];
    cx = fmaf(r0, px, fmaf(r1, py, fmaf(r2, pz, t0)));
    cy = fmaf(r3, px, fmaf(r4, py, fmaf(r5, pz, t1)));
    cz = fmaf(r6, px, fmaf(r7, py, fmaf(r8, pz, t2)));
  }
  const float ax = -2.f*cx, ay = -2.f*cy, az = -2.f*cz;
  __syncthreads();
  u32 b0=~0u, b1=~0u, b2=~0u, b3=~0u, b4=~0u, b5=~0u;
#pragma unroll 8
  for (int j = 0; j < CHUNK; ++j) {
    float4 c = sc[j];
    float s = fmaf(c.x, ax, fmaf(c.y, ay, fmaf(c.z, az, c.w)));  // |c|^2 - 2c.x
    u32 bits = __float_as_uint(s);
    u32 u = bits ^ ((u32)((int)bits >> 31) | 0x80000000u);       // order-preserving map
    u32 key = (u & 0xFFFFF000u) | (u32)(j0 + j);
    TOP6_INSERT_ILP(key);
  }
  u32* o = part + (size_t)(cloud * NCHUNK + chunk) * KNN * NP + ci;
  o[0*NP] = b0; o[1*NP] = b1; o[2*NP] = b2;
  o[3*NP] = b3; o[4*NP] = b4; o[5*NP] = b5;
}

// K3: 32 blocks (cloud x center-block) fold 16 chunk-lists, gather neighbor
// coords, publish signed f64 block sums via device atomics; the LAST block
// (ticket) computes the mean and the L1 loss. Fixed summation order ->
// bit-deterministic regardless of which block finishes last.
__global__ __launch_bounds__(256) void k3_merge_final(const u32* __restrict__ part,
                                                      const float* __restrict__ rx,
                                                      const float* __restrict__ ry,
                                                      const float* __restrict__ rz,
                                                      const float* __restrict__ ycloud,
                                                      const float* __restrict__ pred,
                                                      double* __restrict__ blockpart,
                                                      u32* __restrict__ counter,
                                                      float* __restrict__ out) {
  const int tid = threadIdx.x;
  const int lane = tid & 63, wv = tid >> 6;
  const int cloud = blockIdx.x >> 4, cblk = blockIdx.x & 15;
  const int ci = cblk * 256 + tid;
  u32 b0=~0u, b1=~0u, b2=~0u, b3=~0u, b4=~0u, b5=~0u;
  for (int c = 0; c < NCHUNK; ++c) {
    const u32* p = part + (size_t)(cloud * NCHUNK + c) * KNN * NP + ci;
#pragma unroll
    for (int e = 0; e < KNN; ++e) {
      u32 key = p[(size_t)e * NP];
      TOP6_INSERT_ILP(key);
    }
  }
  u32 bk[KNN] = { b0, b1, b2, b3, b4, b5 };
  float s0 = 0.f, s1 = 0.f, s2 = 0.f;
  if (cloud == 0) {
#pragma unroll
    for (int k = 0; k < KNN; ++k) {
      int idx = (int)(bk[k] & 0xFFFu);
      s0 += rx[idx]; s1 += ry[idx]; s2 += rz[idx];
    }
  } else {
#pragma unroll
    for (int k = 0; k < KNN; ++k) {
      int idx = (int)(bk[k] & 0xFFFu);
      s0 += ycloud[idx]; s1 += ycloud[NP + idx]; s2 += ycloud[2*NP + idx];
    }
  }
  const double sgn = cloud ? -1.0 : 1.0;
  double v0 = wave_reduce(sgn * (double)s0);
  double v1 = wave_reduce(sgn * (double)s1);
  double v2 = wave_reduce(sgn * (double)s2);
  __shared__ double wred[4][3];
  __shared__ int lastFlag;
  if (lane == 0) { wred[wv][0] = v0; wred[wv][1] = v1; wred[wv][2] = v2; }
  __syncthreads();
  if (tid == 0) {
    for (int q = 0; q < 3; ++q) {
      double B = wred[0][q] + wred[1][q] + wred[2][q] + wred[3][q];
      atomicExch((u64*)&blockpart[blockIdx.x * 3 + q], (u64)__double_as_longlong(B));
    }
    __threadfence();
    u32 t = atomicAdd(counter, 1u);
    lastFlag = (t == 31u);
  }
  __syncthreads();
  if (!lastFlag) return;

  // ---- finisher: mean laplace diff, then L1 loss ----
  __shared__ double bp[96];
  __threadfence();
  if (tid < 96)
    bp[tid] = __longlong_as_double((long long)atomicAdd((u64*)&blockpart[tid], 0ULL));
  __syncthreads();
  __shared__ float m[3];
  if (tid == 0) {
    double a0 = 0.0, a1 = 0.0, a2 = 0.0;
    for (int b = 0; b < 32; ++b) {
      a0 += bp[b*3 + 0]; a1 += bp[b*3 + 1]; a2 += bp[b*3 + 2];
    }
    const double sc = 0.2 / (double)NP;   // /(k-1), then mean over N
    m[0] = (float)(a0 * sc); m[1] = (float)(a1 * sc); m[2] = (float)(a2 * sc);
  }
  __syncthreads();
  const float m0 = m[0], m1 = m[1], m2 = m[2];
  double s = 0.0;
  for (int i = tid; i < NP; i += 256) {
    s += (double)fabsf(rx[i] - m0 - pred[i]);
    s += (double)fabsf(ry[i] - m1 - pred[NP + i]);
    s += (double)fabsf(rz[i] - m2 - pred[2*NP + i]);
  }
  double v = wave_reduce(s);
  __shared__ double fred[4];
  if (lane == 0) fred[wv] = v;
  __syncthreads();
  if (tid == 0)
    out[0] = (float)((fred[0] + fred[1] + fred[2] + fred[3]) / (3.0 * (double)NP));
}

extern "C" void kernel_launch(void* const* d_in, const int* in_sizes, int n_in,
                              void* d_out, int out_size, void* d_ws, size_t ws_size,
                              hipStream_t stream) {
  const float* in   = (const float*)d_in[0];
  const float* sf   = (const float*)d_in[1];
  const float* y1   = (const float*)d_in[2];
  const float* pred = (const float*)d_in[3];

  u32* part = (u32*)d_ws;                                   // 2*16*6*4096 u32 = 3.15 MB
  double* blockpart = (double*)(part + (size_t)2*NCHUNK*KNN*NP);  // 96 doubles (8-aligned)
  u32* counter = (u32*)(blockpart + 96);
  float* Rt = (float*)(counter + 4);                        // 12 floats
  float* rx = Rt + 12;
  float* ry = rx + NP;
  float* rz = ry + NP;

  k1_kabsch<<<1, 256, 0, stream>>>(in, sf, Rt, counter);
  k2_scan<<<dim3(NCHUNK, 16, 2), 256, 0, stream>>>(in, y1, Rt, part, rx, ry, rz);
  k3_merge_final<<<32, 256, 0, stream>>>(part, rx, ry, rz, y1, pred,
                                         blockpart, counter, (float*)d_out);
}